// Round 1
// baseline (7034.779 us; speedup 1.0000x reference)
//
#include <hip/hip_runtime.h>
#include <cmath>

// ---------------- problem constants (from reference setup) ----------------
constexpr int B   = 32;
constexpr int LP  = 64;    // path length
constexpr int L   = 128;   // time steps
constexpr int E   = 32;    // emp_size
constexpr int BE  = B * E; // 1024 rows
constexpr int H   = 128;   // HIDDEN
constexpr int M   = 256;   // MLP_SIZE
constexpr int N   = 4;     // NOISE
constexpr int SIG = 30;    // 2+4+8+16
constexpr int IN  = 1 + H + SIG; // 159
constexpr int KP  = 160;   // padded K for layer 1
constexpr int ROWS = 4;    // rows per block
constexpr int NBLK = BE / ROWS; // 256 blocks

// ws layout (floats) when transposed weights fit:
constexpr size_t OFF_FW1 = 0;                       // [256][160]
constexpr size_t OFF_FW2 = OFF_FW1 + 256 * 160;     // [256][256]
constexpr size_t OFF_FW3 = OFF_FW2 + 256 * 256;     // [128][256]
constexpr size_t OFF_GW1 = OFF_FW3 + 128 * 256;     // [256][160]
constexpr size_t OFF_GW2 = OFF_GW1 + 256 * 160;     // [256][256]
constexpr size_t OFF_GW3 = OFF_GW2 + 256 * 256;     // [512][256]
constexpr size_t OFF_H0  = OFF_GW3 + 512 * 256;     // [32][128]
constexpr size_t OFF_C0  = OFF_H0 + 32 * H;         // [32][30]
constexpr size_t OFF_YC  = OFF_C0 + 32 * SIG;       // [32]
constexpr size_t WS_TOT  = OFF_YC + 32;             // 381920 floats

// ---------------- prep kernel: signature + h0 + readout const + W^T -------
__global__ __launch_bounds__(256) void prep_kernel(
    const float* __restrict__ paths, const float* __restrict__ Wi, const float* __restrict__ bi,
    const float* __restrict__ Wr, const float* __restrict__ br,
    const float* __restrict__ fW1, const float* __restrict__ fW2, const float* __restrict__ fW3,
    const float* __restrict__ gW1, const float* __restrict__ gW2, const float* __restrict__ gW3,
    float* __restrict__ wsbase, float* __restrict__ h0u, float* __restrict__ c0u,
    float* __restrict__ yc, int do_tr)
{
  const int tid = threadIdx.x;
  if (blockIdx.x == 0) {
    __shared__ float sC0[32][SIG];
    __shared__ float sXT[32];
    if (tid < 32) {
      const float* pp = paths + (size_t)tid * LP * 2;
      float S1[2], S2[4], S3[8], S4[16];
      float T1[2], T2[4], T3[8], T4[16];
      {
        float a0 = pp[2] - pp[0], a1 = pp[3] - pp[1];
        S1[0] = a0; S1[1] = a1;
        S2[0] = a0 * a0 * 0.5f; S2[1] = a0 * a1 * 0.5f;
        S2[2] = a1 * a0 * 0.5f; S2[3] = a1 * a1 * 0.5f;
        for (int c = 0; c < 4; c++) { S3[c*2] = S2[c]*a0*(1.f/3.f); S3[c*2+1] = S2[c]*a1*(1.f/3.f); }
        for (int c = 0; c < 8; c++) { S4[c*2] = S3[c]*a0*0.25f;     S4[c*2+1] = S3[c]*a1*0.25f; }
      }
      for (int j = 1; j < LP - 1; j++) {
        float a0 = pp[(j+1)*2]   - pp[j*2];
        float a1 = pp[(j+1)*2+1] - pp[j*2+1];
        T1[0] = a0; T1[1] = a1;
        T2[0] = a0*a0*0.5f; T2[1] = a0*a1*0.5f; T2[2] = a1*a0*0.5f; T2[3] = a1*a1*0.5f;
        for (int c = 0; c < 4; c++) { T3[c*2] = T2[c]*a0*(1.f/3.f); T3[c*2+1] = T2[c]*a1*(1.f/3.f); }
        for (int c = 0; c < 8; c++) { T4[c*2] = T3[c]*a0*0.25f;     T4[c*2+1] = T3[c]*a1*0.25f; }
        float U2[4], U3[8], U4[16];
        for (int i = 0; i < 4;  i++) U2[i] = S2[i] + T2[i];
        for (int a = 0; a < 2; a++) for (int b = 0; b < 2; b++) U2[a*2+b] += S1[a]*T1[b];
        for (int i = 0; i < 8;  i++) U3[i] = S3[i] + T3[i];
        for (int a = 0; a < 2; a++) for (int m = 0; m < 4; m++) U3[a*4+m] += S1[a]*T2[m];
        for (int a = 0; a < 4; a++) for (int b = 0; b < 2; b++) U3[a*2+b] += S2[a]*T1[b];
        for (int i = 0; i < 16; i++) U4[i] = S4[i] + T4[i];
        for (int a = 0; a < 2; a++) for (int m = 0; m < 8; m++) U4[a*8+m] += S1[a]*T3[m];
        for (int a = 0; a < 4; a++) for (int m = 0; m < 4; m++) U4[a*4+m] += S2[a]*T2[m];
        for (int a = 0; a < 8; a++) for (int b = 0; b < 2; b++) U4[a*2+b] += S3[a]*T1[b];
        for (int i = 0; i < 4;  i++) S2[i] = U2[i];
        for (int i = 0; i < 8;  i++) S3[i] = U3[i];
        for (int i = 0; i < 16; i++) S4[i] = U4[i];
        S1[0] += T1[0]; S1[1] += T1[1];
      }
      sXT[tid] = pp[(LP-1)*2 + 1];
      float* dst = &sC0[tid][0];
      dst[0] = S1[0]; dst[1] = S1[1];
      for (int i = 0; i < 4;  i++) dst[2  + i] = S2[i];
      for (int i = 0; i < 8;  i++) dst[6  + i] = S3[i];
      for (int i = 0; i < 16; i++) dst[14 + i] = S4[i];
    }
    __syncthreads();
    for (int idx = tid; idx < 32 * H; idx += 256) {
      int p = idx >> 7, h = idx & (H - 1);
      float acc = bi[h] + sXT[p] * Wi[h];
      const float* c = &sC0[p][0];
      for (int j = 0; j < SIG; j++) acc += c[j] * Wi[(1 + j) * H + h];
      h0u[idx] = acc;
    }
    if (tid < 32) {
      float acc = br[0];
      for (int j = 0; j < SIG; j++) acc += sC0[tid][j] * Wr[H + j];
      yc[tid] = acc;
    }
    for (int idx = tid; idx < 32 * SIG; idx += 256)
      c0u[idx] = sC0[idx / SIG][idx % SIG];
  } else if (do_tr) {
    const float* srcs[6] = { fW1, fW2, fW3, gW1, gW2, gW3 };
    const int Ks[6]  = { IN, M, M, IN, M, M };
    const int Cs[6]  = { M, M, H, M, M, H * N };
    const int Kps[6] = { KP, M, M, KP, M, M };
    const long offs[7] = { (long)OFF_FW1, (long)OFF_FW2, (long)OFF_FW3,
                           (long)OFF_GW1, (long)OFF_GW2, (long)OFF_GW3, (long)OFF_H0 };
    const long total = (long)OFF_H0;
    const long stride = (long)(gridDim.x - 1) * 256;
    for (long idx = (long)(blockIdx.x - 1) * 256 + tid; idx < total; idx += stride) {
      int m = 0;
      while (idx >= offs[m + 1]) m++;
      long rel = idx - offs[m];
      int Kp = Kps[m];
      int c = (int)(rel / Kp);
      int k = (int)(rel - (long)c * Kp);
      wsbase[idx] = (k < Ks[m]) ? srcs[m][(size_t)k * Cs[m] + c] : 0.f;
    }
  }
}

// ---------------- MLP layer helpers ----------------
__device__ __forceinline__ float lipswish_f(float x) {
  return 0.909f * x * (1.f / (1.f + expf(-x)));
}

// C=256 layer, 4 rows. TR: W is [256][Kp] (row-contiguous). !TR: W is [K][256].
template<bool TR>
__device__ __forceinline__ void layer_c256(const float* __restrict__ W, const float* __restrict__ bias,
                                           const float* __restrict__ xin, int xs, int K, int Kp,
                                           float* __restrict__ outp, int tid)
{
  const int col = tid;
  float a0 = 0.f, a1 = 0.f, a2 = 0.f, a3 = 0.f;
  if constexpr (TR) {
    const float* wp = W + (size_t)col * Kp;
    #pragma unroll 4
    for (int k = 0; k < Kp; k += 4) {
      const float4 w  = *(const float4*)(wp + k);
      const float4 x0 = *(const float4*)(xin + k);
      const float4 x1 = *(const float4*)(xin + xs + k);
      const float4 x2 = *(const float4*)(xin + 2 * xs + k);
      const float4 x3 = *(const float4*)(xin + 3 * xs + k);
      a0 += x0.x*w.x + x0.y*w.y + x0.z*w.z + x0.w*w.w;
      a1 += x1.x*w.x + x1.y*w.y + x1.z*w.z + x1.w*w.w;
      a2 += x2.x*w.x + x2.y*w.y + x2.z*w.z + x2.w*w.w;
      a3 += x3.x*w.x + x3.y*w.y + x3.z*w.z + x3.w*w.w;
    }
  } else {
    for (int k = 0; k < K; k++) {
      float w = W[(size_t)k * M + col];
      a0 += xin[k] * w; a1 += xin[xs + k] * w;
      a2 += xin[2 * xs + k] * w; a3 += xin[3 * xs + k] * w;
    }
  }
  const float b = bias[col];
  a0 = lipswish_f(a0 + b); a1 = lipswish_f(a1 + b);
  a2 = lipswish_f(a2 + b); a3 = lipswish_f(a3 + b);
  outp[col] = a0; outp[M + col] = a1; outp[2 * M + col] = a2; outp[3 * M + col] = a3;
}

// C=128 layer (f output), K=256, tanh. Threads split: tid>>7 picks row pair.
template<bool TR>
__device__ __forceinline__ void layer_c128(const float* __restrict__ W, const float* __restrict__ bias,
                                           const float* __restrict__ xin, int xs,
                                           float* __restrict__ outp, int tid)
{
  const int half = tid >> 7;
  const int col = tid & 127;
  const float* x0p = xin + (2 * half) * xs;
  const float* x1p = xin + (2 * half + 1) * xs;
  float a0 = 0.f, a1 = 0.f;
  if constexpr (TR) {
    const float* wp = W + (size_t)col * M;
    #pragma unroll 4
    for (int k = 0; k < M; k += 4) {
      const float4 w  = *(const float4*)(wp + k);
      const float4 x0 = *(const float4*)(x0p + k);
      const float4 x1 = *(const float4*)(x1p + k);
      a0 += x0.x*w.x + x0.y*w.y + x0.z*w.z + x0.w*w.w;
      a1 += x1.x*w.x + x1.y*w.y + x1.z*w.z + x1.w*w.w;
    }
  } else {
    for (int k = 0; k < M; k++) {
      float w = W[(size_t)k * H + col];
      a0 += x0p[k] * w; a1 += x1p[k] * w;
    }
  }
  const float b = bias[col];
  outp[(2 * half) * H + col]     = tanhf(a0 + b);
  outp[(2 * half + 1) * H + col] = tanhf(a1 + b);
}

// C=512 layer (g output), K=256, tanh. Each thread owns cols tid and tid+256.
template<bool TR>
__device__ __forceinline__ void layer_c512(const float* __restrict__ W, const float* __restrict__ bias,
                                           const float* __restrict__ xin, int xs,
                                           float* __restrict__ outp, int tid)
{
  const int c0 = tid, c1 = tid + 256;
  float a00 = 0.f, a01 = 0.f, a02 = 0.f, a03 = 0.f;
  float a10 = 0.f, a11 = 0.f, a12 = 0.f, a13 = 0.f;
  if constexpr (TR) {
    const float* wp0 = W + (size_t)c0 * M;
    const float* wp1 = W + (size_t)c1 * M;
    #pragma unroll 2
    for (int k = 0; k < M; k += 4) {
      const float4 w0 = *(const float4*)(wp0 + k);
      const float4 w1 = *(const float4*)(wp1 + k);
      const float4 x0 = *(const float4*)(xin + k);
      const float4 x1 = *(const float4*)(xin + xs + k);
      const float4 x2 = *(const float4*)(xin + 2 * xs + k);
      const float4 x3 = *(const float4*)(xin + 3 * xs + k);
      a00 += x0.x*w0.x + x0.y*w0.y + x0.z*w0.z + x0.w*w0.w;
      a01 += x1.x*w0.x + x1.y*w0.y + x1.z*w0.z + x1.w*w0.w;
      a02 += x2.x*w0.x + x2.y*w0.y + x2.z*w0.z + x2.w*w0.w;
      a03 += x3.x*w0.x + x3.y*w0.y + x3.z*w0.z + x3.w*w0.w;
      a10 += x0.x*w1.x + x0.y*w1.y + x0.z*w1.z + x0.w*w1.w;
      a11 += x1.x*w1.x + x1.y*w1.y + x1.z*w1.z + x1.w*w1.w;
      a12 += x2.x*w1.x + x2.y*w1.y + x2.z*w1.z + x2.w*w1.w;
      a13 += x3.x*w1.x + x3.y*w1.y + x3.z*w1.z + x3.w*w1.w;
    }
  } else {
    for (int k = 0; k < M; k++) {
      float w0 = W[(size_t)k * (H * N) + c0];
      float w1 = W[(size_t)k * (H * N) + c1];
      float x0 = xin[k], x1 = xin[xs + k], x2 = xin[2 * xs + k], x3 = xin[3 * xs + k];
      a00 += x0 * w0; a01 += x1 * w0; a02 += x2 * w0; a03 += x3 * w0;
      a10 += x0 * w1; a11 += x1 * w1; a12 += x2 * w1; a13 += x3 * w1;
    }
  }
  const float b0 = bias[c0], b1 = bias[c1];
  outp[0 * (H * N) + c0] = tanhf(a00 + b0);
  outp[1 * (H * N) + c0] = tanhf(a01 + b0);
  outp[2 * (H * N) + c0] = tanhf(a02 + b0);
  outp[3 * (H * N) + c0] = tanhf(a03 + b0);
  outp[0 * (H * N) + c1] = tanhf(a10 + b1);
  outp[1 * (H * N) + c1] = tanhf(a11 + b1);
  outp[2 * (H * N) + c1] = tanhf(a12 + b1);
  outp[3 * (H * N) + c1] = tanhf(a13 + b1);
}

// ---------------- main persistent SDE kernel ----------------
template<bool TR>
__global__ __launch_bounds__(256, 1) void sde_kernel(
    const float* __restrict__ ts, const float* __restrict__ dW,
    const float* __restrict__ fb1, const float* __restrict__ fb2, const float* __restrict__ fb3,
    const float* __restrict__ gb1, const float* __restrict__ gb2, const float* __restrict__ gb3,
    const float* __restrict__ Wr,
    const float* __restrict__ WF1, const float* __restrict__ WF2, const float* __restrict__ WF3,
    const float* __restrict__ WG1, const float* __restrict__ WG2, const float* __restrict__ WG3,
    const float* __restrict__ h0u, const float* __restrict__ c0u, const float* __restrict__ ycp,
    float* __restrict__ out)
{
  __shared__ float xv[ROWS * KP];     // MLP input [t, z(128), c0(30), pad]
  __shared__ float hA[ROWS * M];
  __shared__ float hB[ROWS * M];
  __shared__ float fo[ROWS * H];      // drift output
  __shared__ float go[ROWS * H * N];  // diffusion output
  __shared__ float zz[ROWS * H];      // z (current / mid during step)
  __shared__ float zzh[ROWS * H];     // zh

  const int tid = threadIdx.x;
  const int r0 = blockIdx.x * ROWS;
  const int p = r0 >> 5;              // unique path index (E=32, ROWS=4 -> uniform per block)

  const float ts0 = ts[0];
  const float dtv = ts[1] - ts0;
  const int lane = tid & 63;
  const int wrow = tid >> 6;
  const float wr_lo = Wr[lane];
  const float wr_hi = Wr[lane + 64];
  const float ycv = ycp[p];

  // ---- init: z = zh = h0, xv = [ts0, h0, c0, 0] ----
  for (int idx = tid; idx < ROWS * H; idx += 256) {
    int i = idx >> 7, h = idx & (H - 1);
    float v = h0u[p * H + h];
    zz[idx] = v; zzh[idx] = v;
    xv[i * KP + 1 + h] = v;
  }
  if (tid < ROWS * SIG) {
    int i = tid / SIG, j = tid % SIG;
    xv[i * KP + 1 + H + j] = c0u[p * SIG + j];
  }
  if (tid < ROWS) { xv[tid * KP] = ts0; xv[tid * KP + IN] = 0.f; }
  __syncthreads();

  // ---- f0, g0 ----
  layer_c256<TR>(WF1, fb1, xv, KP, IN, KP, hA, tid); __syncthreads();
  layer_c256<TR>(WF2, fb2, hA, M, M, M, hB, tid);    __syncthreads();
  layer_c128<TR>(WF3, fb3, hB, M, fo, tid);          __syncthreads();
  layer_c256<TR>(WG1, gb1, xv, KP, IN, KP, hA, tid); __syncthreads();
  layer_c256<TR>(WG2, gb2, hA, M, M, M, hB, tid);    __syncthreads();
  layer_c512<TR>(WG3, gb3, hB, M, go, tid);          __syncthreads();

  // ---- emit t=0 ----
  {
    float part = zz[wrow * H + lane] * wr_lo + zz[wrow * H + lane + 64] * wr_hi;
    for (int off = 32; off; off >>= 1) part += __shfl_down(part, off, 64);
    if (lane == 0) {
      size_t o = ((size_t)(r0 + wrow) * L + 0) * 2;
      out[o] = ts0; out[o + 1] = part + ycv;
    }
  }
  __syncthreads();

  // ---- time loop ----
  for (int t = 1; t < L; t++) {
    const float t1 = ts[t];
    const float4* dwp = (const float4*)(dW + ((size_t)(t - 1) * BE + r0) * N);

    // phase A: zh1 = 2z - zh + fh*dt + gh.dW ; zmid = z + 0.5dt*fh + 0.5*gh.dW
    for (int e = tid; e < ROWS * H; e += 256) {
      int i = e >> 7, h = e & (H - 1);
      float4 dwv = dwp[i];
      float4 g4 = *(const float4*)(go + i * (H * N) + h * 4);
      float gdot = g4.x * dwv.x + g4.y * dwv.y + g4.z * dwv.z + g4.w * dwv.w;
      float fh = fo[e];
      float zo = zz[e];
      float nzh = 2.f * zo - zzh[e] + fh * dtv + gdot;
      zz[e] = zo + 0.5f * dtv * fh + 0.5f * gdot;
      zzh[e] = nzh;
      xv[i * KP + 1 + h] = nzh;
    }
    if (tid < ROWS) xv[tid * KP] = t1;
    __syncthreads();

    // f1, g1 at (t1, zh1)
    layer_c256<TR>(WF1, fb1, xv, KP, IN, KP, hA, tid); __syncthreads();
    layer_c256<TR>(WF2, fb2, hA, M, M, M, hB, tid);    __syncthreads();
    layer_c128<TR>(WF3, fb3, hB, M, fo, tid);          __syncthreads();
    layer_c256<TR>(WG1, gb1, xv, KP, IN, KP, hA, tid); __syncthreads();
    layer_c256<TR>(WG2, gb2, hA, M, M, M, hB, tid);    __syncthreads();
    layer_c512<TR>(WG3, gb3, hB, M, go, tid);          __syncthreads();

    // phase B: z1 = zmid + 0.5dt*f1 + 0.5*g1.dW
    for (int e = tid; e < ROWS * H; e += 256) {
      int i = e >> 7, h = e & (H - 1);
      float4 dwv = dwp[i];
      float4 g4 = *(const float4*)(go + i * (H * N) + h * 4);
      float gdot = g4.x * dwv.x + g4.y * dwv.y + g4.z * dwv.z + g4.w * dwv.w;
      zz[e] = zz[e] + 0.5f * dtv * fo[e] + 0.5f * gdot;
    }
    __syncthreads();

    // emit y_t
    {
      float part = zz[wrow * H + lane] * wr_lo + zz[wrow * H + lane + 64] * wr_hi;
      for (int off = 32; off; off >>= 1) part += __shfl_down(part, off, 64);
      if (lane == 0) {
        size_t o = ((size_t)(r0 + wrow) * L + t) * 2;
        out[o] = t1; out[o + 1] = part + ycv;
      }
    }
    __syncthreads();
  }
}

// ---------------- launch ----------------
extern "C" void kernel_launch(void* const* d_in, const int* in_sizes, int n_in,
                              void* d_out, int out_size, void* d_ws, size_t ws_size,
                              hipStream_t stream) {
  const float* ts    = (const float*)d_in[0];
  const float* paths = (const float*)d_in[1];
  const float* dWn   = (const float*)d_in[2];
  const float* Wi    = (const float*)d_in[3];
  const float* bi    = (const float*)d_in[4];
  const float* fW1   = (const float*)d_in[5];
  const float* fb1   = (const float*)d_in[6];
  const float* fW2   = (const float*)d_in[7];
  const float* fb2   = (const float*)d_in[8];
  const float* fW3   = (const float*)d_in[9];
  const float* fb3   = (const float*)d_in[10];
  const float* gW1   = (const float*)d_in[11];
  const float* gb1   = (const float*)d_in[12];
  const float* gW2   = (const float*)d_in[13];
  const float* gb2   = (const float*)d_in[14];
  const float* gW3   = (const float*)d_in[15];
  const float* gb3   = (const float*)d_in[16];
  const float* Wr    = (const float*)d_in[17];
  const float* br    = (const float*)d_in[18];
  float* out = (float*)d_out;
  float* wsf = (float*)d_ws;

  const bool tr = ws_size >= WS_TOT * sizeof(float);
  if (tr) {
    prep_kernel<<<64, 256, 0, stream>>>(paths, Wi, bi, Wr, br,
                                        fW1, fW2, fW3, gW1, gW2, gW3,
                                        wsf, wsf + OFF_H0, wsf + OFF_C0, wsf + OFF_YC, 1);
    sde_kernel<true><<<NBLK, 256, 0, stream>>>(
        ts, dWn, fb1, fb2, fb3, gb1, gb2, gb3, Wr,
        wsf + OFF_FW1, wsf + OFF_FW2, wsf + OFF_FW3,
        wsf + OFF_GW1, wsf + OFF_GW2, wsf + OFF_GW3,
        wsf + OFF_H0, wsf + OFF_C0, wsf + OFF_YC, out);
  } else {
    // small-workspace fallback: only h0/c0/yc in ws, weights read untransposed
    float* h0u = wsf;
    float* c0u = wsf + 32 * H;
    float* yc  = wsf + 32 * H + 32 * SIG;
    prep_kernel<<<1, 256, 0, stream>>>(paths, Wi, bi, Wr, br,
                                       fW1, fW2, fW3, gW1, gW2, gW3,
                                       wsf, h0u, c0u, yc, 0);
    sde_kernel<false><<<NBLK, 256, 0, stream>>>(
        ts, dWn, fb1, fb2, fb3, gb1, gb2, gb3, Wr,
        fW1, fW2, fW3, gW1, gW2, gW3,
        h0u, c0u, yc, out);
  }
}

// Round 2
// 6079.257 us; speedup vs baseline: 1.1572x; 1.1572x over previous
//
#include <hip/hip_runtime.h>
#include <cmath>

// ---------------- problem constants (from reference setup) ----------------
constexpr int B   = 32;
constexpr int LP  = 64;    // path length
constexpr int L   = 128;   // time steps
constexpr int E   = 32;    // emp_size
constexpr int BE  = B * E; // 1024 rows
constexpr int H   = 128;   // HIDDEN
constexpr int M   = 256;   // MLP_SIZE
constexpr int N   = 4;     // NOISE
constexpr int SIG = 30;    // 2+4+8+16
constexpr int IN  = 1 + H + SIG; // 159
constexpr int KP  = 160;   // padded K for layer 1
constexpr int ROWS = 4;    // rows per block
constexpr int NBLK = BE / ROWS; // 256 blocks
constexpr int TPB  = 1024; // threads per block (16 waves -> 4 waves/SIMD)

// ws layout (floats) when transposed weights fit:
constexpr size_t OFF_FW1 = 0;                       // [256][160]
constexpr size_t OFF_FW2 = OFF_FW1 + 256 * 160;     // [256][256]
constexpr size_t OFF_FW3 = OFF_FW2 + 256 * 256;     // [128][256]
constexpr size_t OFF_GW1 = OFF_FW3 + 128 * 256;     // [256][160]
constexpr size_t OFF_GW2 = OFF_GW1 + 256 * 160;     // [256][256]
constexpr size_t OFF_GW3 = OFF_GW2 + 256 * 256;     // [512][256]
constexpr size_t OFF_H0  = OFF_GW3 + 512 * 256;     // [32][128]
constexpr size_t OFF_C0  = OFF_H0 + 32 * H;         // [32][30]
constexpr size_t OFF_YC  = OFF_C0 + 32 * SIG;       // [32]
constexpr size_t WS_TOT  = OFF_YC + 32;             // 381920 floats

// ---------------- prep kernel: signature + h0 + readout const + W^T -------
__global__ __launch_bounds__(256) void prep_kernel(
    const float* __restrict__ paths, const float* __restrict__ Wi, const float* __restrict__ bi,
    const float* __restrict__ Wr, const float* __restrict__ br,
    const float* __restrict__ fW1, const float* __restrict__ fW2, const float* __restrict__ fW3,
    const float* __restrict__ gW1, const float* __restrict__ gW2, const float* __restrict__ gW3,
    float* __restrict__ wsbase, float* __restrict__ h0u, float* __restrict__ c0u,
    float* __restrict__ yc, int do_tr)
{
  const int tid = threadIdx.x;
  if (blockIdx.x == 0) {
    __shared__ float sC0[32][SIG];
    __shared__ float sXT[32];
    if (tid < 32) {
      const float* pp = paths + (size_t)tid * LP * 2;
      float S1[2], S2[4], S3[8], S4[16];
      float T1[2], T2[4], T3[8], T4[16];
      {
        float a0 = pp[2] - pp[0], a1 = pp[3] - pp[1];
        S1[0] = a0; S1[1] = a1;
        S2[0] = a0 * a0 * 0.5f; S2[1] = a0 * a1 * 0.5f;
        S2[2] = a1 * a0 * 0.5f; S2[3] = a1 * a1 * 0.5f;
        for (int c = 0; c < 4; c++) { S3[c*2] = S2[c]*a0*(1.f/3.f); S3[c*2+1] = S2[c]*a1*(1.f/3.f); }
        for (int c = 0; c < 8; c++) { S4[c*2] = S3[c]*a0*0.25f;     S4[c*2+1] = S3[c]*a1*0.25f; }
      }
      for (int j = 1; j < LP - 1; j++) {
        float a0 = pp[(j+1)*2]   - pp[j*2];
        float a1 = pp[(j+1)*2+1] - pp[j*2+1];
        T1[0] = a0; T1[1] = a1;
        T2[0] = a0*a0*0.5f; T2[1] = a0*a1*0.5f; T2[2] = a1*a0*0.5f; T2[3] = a1*a1*0.5f;
        for (int c = 0; c < 4; c++) { T3[c*2] = T2[c]*a0*(1.f/3.f); T3[c*2+1] = T2[c]*a1*(1.f/3.f); }
        for (int c = 0; c < 8; c++) { T4[c*2] = T3[c]*a0*0.25f;     T4[c*2+1] = T3[c]*a1*0.25f; }
        float U2[4], U3[8], U4[16];
        for (int i = 0; i < 4;  i++) U2[i] = S2[i] + T2[i];
        for (int a = 0; a < 2; a++) for (int b = 0; b < 2; b++) U2[a*2+b] += S1[a]*T1[b];
        for (int i = 0; i < 8;  i++) U3[i] = S3[i] + T3[i];
        for (int a = 0; a < 2; a++) for (int m = 0; m < 4; m++) U3[a*4+m] += S1[a]*T2[m];
        for (int a = 0; a < 4; a++) for (int b = 0; b < 2; b++) U3[a*2+b] += S2[a]*T1[b];
        for (int i = 0; i < 16; i++) U4[i] = S4[i] + T4[i];
        for (int a = 0; a < 2; a++) for (int m = 0; m < 8; m++) U4[a*8+m] += S1[a]*T3[m];
        for (int a = 0; a < 4; a++) for (int m = 0; m < 4; m++) U4[a*4+m] += S2[a]*T2[m];
        for (int a = 0; a < 8; a++) for (int b = 0; b < 2; b++) U4[a*2+b] += S3[a]*T1[b];
        for (int i = 0; i < 4;  i++) S2[i] = U2[i];
        for (int i = 0; i < 8;  i++) S3[i] = U3[i];
        for (int i = 0; i < 16; i++) S4[i] = U4[i];
        S1[0] += T1[0]; S1[1] += T1[1];
      }
      sXT[tid] = pp[(LP-1)*2 + 1];
      float* dst = &sC0[tid][0];
      dst[0] = S1[0]; dst[1] = S1[1];
      for (int i = 0; i < 4;  i++) dst[2  + i] = S2[i];
      for (int i = 0; i < 8;  i++) dst[6  + i] = S3[i];
      for (int i = 0; i < 16; i++) dst[14 + i] = S4[i];
    }
    __syncthreads();
    for (int idx = tid; idx < 32 * H; idx += 256) {
      int p = idx >> 7, h = idx & (H - 1);
      float acc = bi[h] + sXT[p] * Wi[h];
      const float* c = &sC0[p][0];
      for (int j = 0; j < SIG; j++) acc += c[j] * Wi[(1 + j) * H + h];
      h0u[idx] = acc;
    }
    if (tid < 32) {
      float acc = br[0];
      for (int j = 0; j < SIG; j++) acc += sC0[tid][j] * Wr[H + j];
      yc[tid] = acc;
    }
    for (int idx = tid; idx < 32 * SIG; idx += 256)
      c0u[idx] = sC0[idx / SIG][idx % SIG];
  } else if (do_tr) {
    const float* srcs[6] = { fW1, fW2, fW3, gW1, gW2, gW3 };
    const int Ks[6]  = { IN, M, M, IN, M, M };
    const int Cs[6]  = { M, M, H, M, M, H * N };
    const int Kps[6] = { KP, M, M, KP, M, M };
    const long offs[7] = { (long)OFF_FW1, (long)OFF_FW2, (long)OFF_FW3,
                           (long)OFF_GW1, (long)OFF_GW2, (long)OFF_GW3, (long)OFF_H0 };
    const long total = (long)OFF_H0;
    const long stride = (long)(gridDim.x - 1) * 256;
    for (long idx = (long)(blockIdx.x - 1) * 256 + tid; idx < total; idx += stride) {
      int m = 0;
      while (idx >= offs[m + 1]) m++;
      long rel = idx - offs[m];
      int Kp = Kps[m];
      int c = (int)(rel / Kp);
      int k = (int)(rel - (long)c * Kp);
      wsbase[idx] = (k < Ks[m]) ? srcs[m][(size_t)k * Cs[m] + c] : 0.f;
    }
  }
}

// ---------------- MLP layer helpers (split-K over 1024 threads) ----------
__device__ __forceinline__ float lipswish_f(float x) {
  return 0.909f * x * (1.f / (1.f + expf(-x)));
}

// C=256 layer, 4 rows, K-split-4. TR: W is [256][Kp]. !TR: W is [K][256].
// pp: 4096-float LDS scratch. Two internal barriers.
template<bool TR>
__device__ __forceinline__ void layer_c256(const float* __restrict__ W, const float* __restrict__ bias,
                                           const float* __restrict__ xin, int xs, int Kreal, int Kp,
                                           float* __restrict__ pp, float* __restrict__ outp, int tid)
{
  const int kq  = tid >> 8;      // 0..3
  const int col = tid & 255;
  const int K4  = Kp >> 2;
  const int k0  = kq * K4;
  float a0 = 0.f, a1 = 0.f, a2 = 0.f, a3 = 0.f;
  if constexpr (TR) {
    const float* wp = W + (size_t)col * Kp + k0;
    const float* xp = xin + k0;
    #pragma unroll 4
    for (int k = 0; k < K4; k += 4) {
      const float4 w  = *(const float4*)(wp + k);
      const float4 x0 = *(const float4*)(xp + k);
      const float4 x1 = *(const float4*)(xp + xs + k);
      const float4 x2 = *(const float4*)(xp + 2 * xs + k);
      const float4 x3 = *(const float4*)(xp + 3 * xs + k);
      a0 += x0.x*w.x + x0.y*w.y + x0.z*w.z + x0.w*w.w;
      a1 += x1.x*w.x + x1.y*w.y + x1.z*w.z + x1.w*w.w;
      a2 += x2.x*w.x + x2.y*w.y + x2.z*w.z + x2.w*w.w;
      a3 += x3.x*w.x + x3.y*w.y + x3.z*w.z + x3.w*w.w;
    }
  } else {
    const int kend = (Kreal < k0 + K4) ? Kreal : (k0 + K4);
    for (int k = k0; k < kend; k++) {
      float w = W[(size_t)k * M + col];
      a0 += xin[k] * w; a1 += xin[xs + k] * w;
      a2 += xin[2 * xs + k] * w; a3 += xin[3 * xs + k] * w;
    }
  }
  pp[kq * 1024 + 0 * 256 + col] = a0;
  pp[kq * 1024 + 1 * 256 + col] = a1;
  pp[kq * 1024 + 2 * 256 + col] = a2;
  pp[kq * 1024 + 3 * 256 + col] = a3;
  __syncthreads();
  {
    const int r = tid >> 8, c = tid & 255;
    const int base = r * 256 + c;
    float s = pp[base] + pp[base + 1024] + pp[base + 2048] + pp[base + 3072];
    outp[r * M + c] = lipswish_f(s + bias[c]);
  }
  __syncthreads();
}

// C=128 layer (f output), K=256, tanh, K-split-8.
template<bool TR>
__device__ __forceinline__ void layer_c128(const float* __restrict__ W, const float* __restrict__ bias,
                                           const float* __restrict__ xin, int xs,
                                           float* __restrict__ pp, float* __restrict__ outp, int tid)
{
  const int kq  = tid >> 7;      // 0..7
  const int col = tid & 127;
  const int K4  = M >> 3;        // 32
  const int k0  = kq * K4;
  float a0 = 0.f, a1 = 0.f, a2 = 0.f, a3 = 0.f;
  if constexpr (TR) {
    const float* wp = W + (size_t)col * M + k0;
    const float* xp = xin + k0;
    #pragma unroll 4
    for (int k = 0; k < K4; k += 4) {
      const float4 w  = *(const float4*)(wp + k);
      const float4 x0 = *(const float4*)(xp + k);
      const float4 x1 = *(const float4*)(xp + xs + k);
      const float4 x2 = *(const float4*)(xp + 2 * xs + k);
      const float4 x3 = *(const float4*)(xp + 3 * xs + k);
      a0 += x0.x*w.x + x0.y*w.y + x0.z*w.z + x0.w*w.w;
      a1 += x1.x*w.x + x1.y*w.y + x1.z*w.z + x1.w*w.w;
      a2 += x2.x*w.x + x2.y*w.y + x2.z*w.z + x2.w*w.w;
      a3 += x3.x*w.x + x3.y*w.y + x3.z*w.z + x3.w*w.w;
    }
  } else {
    for (int k = k0; k < k0 + K4; k++) {
      float w = W[(size_t)k * H + col];
      a0 += xin[k] * w; a1 += xin[xs + k] * w;
      a2 += xin[2 * xs + k] * w; a3 += xin[3 * xs + k] * w;
    }
  }
  pp[kq * 512 + 0 * 128 + col] = a0;
  pp[kq * 512 + 1 * 128 + col] = a1;
  pp[kq * 512 + 2 * 128 + col] = a2;
  pp[kq * 512 + 3 * 128 + col] = a3;
  __syncthreads();
  if (tid < 512) {
    const int r = tid >> 7, c = tid & 127;
    const int base = r * 128 + c;
    float s = 0.f;
    #pragma unroll
    for (int q = 0; q < 8; q++) s += pp[base + q * 512];
    outp[r * H + c] = tanhf(s + bias[c]);
  }
  __syncthreads();
}

// C=512 layer (g output), K=256, tanh, K-split-2.
template<bool TR>
__device__ __forceinline__ void layer_c512(const float* __restrict__ W, const float* __restrict__ bias,
                                           const float* __restrict__ xin, int xs,
                                           float* __restrict__ pp, float* __restrict__ outp, int tid)
{
  const int kq  = tid >> 9;      // 0..1
  const int col = tid & 511;
  const int K4  = M >> 1;        // 128
  const int k0  = kq * K4;
  float a0 = 0.f, a1 = 0.f, a2 = 0.f, a3 = 0.f;
  if constexpr (TR) {
    const float* wp = W + (size_t)col * M + k0;
    const float* xp = xin + k0;
    #pragma unroll 4
    for (int k = 0; k < K4; k += 4) {
      const float4 w  = *(const float4*)(wp + k);
      const float4 x0 = *(const float4*)(xp + k);
      const float4 x1 = *(const float4*)(xp + xs + k);
      const float4 x2 = *(const float4*)(xp + 2 * xs + k);
      const float4 x3 = *(const float4*)(xp + 3 * xs + k);
      a0 += x0.x*w.x + x0.y*w.y + x0.z*w.z + x0.w*w.w;
      a1 += x1.x*w.x + x1.y*w.y + x1.z*w.z + x1.w*w.w;
      a2 += x2.x*w.x + x2.y*w.y + x2.z*w.z + x2.w*w.w;
      a3 += x3.x*w.x + x3.y*w.y + x3.z*w.z + x3.w*w.w;
    }
  } else {
    for (int k = k0; k < k0 + K4; k++) {
      float w = W[(size_t)k * (H * N) + col];
      a0 += xin[k] * w; a1 += xin[xs + k] * w;
      a2 += xin[2 * xs + k] * w; a3 += xin[3 * xs + k] * w;
    }
  }
  pp[kq * 2048 + 0 * 512 + col] = a0;
  pp[kq * 2048 + 1 * 512 + col] = a1;
  pp[kq * 2048 + 2 * 512 + col] = a2;
  pp[kq * 2048 + 3 * 512 + col] = a3;
  __syncthreads();
  #pragma unroll
  for (int s2 = 0; s2 < 2; s2++) {
    const int idx = s2 * 1024 + tid;
    const int r = idx >> 9, c = idx & 511;
    const int base = r * 512 + c;
    float s = pp[base] + pp[base + 2048];
    outp[r * (H * N) + c] = tanhf(s + bias[c]);
  }
  __syncthreads();
}

// ---------------- main persistent SDE kernel ----------------
template<bool TR>
__global__ __launch_bounds__(TPB) void sde_kernel(
    const float* __restrict__ ts, const float* __restrict__ dW,
    const float* __restrict__ fb1, const float* __restrict__ fb2, const float* __restrict__ fb3,
    const float* __restrict__ gb1, const float* __restrict__ gb2, const float* __restrict__ gb3,
    const float* __restrict__ Wr,
    const float* __restrict__ WF1, const float* __restrict__ WF2, const float* __restrict__ WF3,
    const float* __restrict__ WG1, const float* __restrict__ WG2, const float* __restrict__ WG3,
    const float* __restrict__ h0u, const float* __restrict__ c0u, const float* __restrict__ ycp,
    float* __restrict__ out)
{
  __shared__ float xv[ROWS * KP];     // MLP input [t, z(128), c0(30), pad]
  __shared__ float hA[ROWS * M];
  __shared__ float hB[ROWS * M];
  __shared__ float fo[ROWS * H];      // drift output
  __shared__ float go[ROWS * H * N];  // diffusion output
  __shared__ float zz[ROWS * H];      // z (current / mid during step)
  __shared__ float zzh[ROWS * H];     // zh
  __shared__ float pp[4096];          // split-K partials scratch (16 KB)

  const int tid = threadIdx.x;
  const int r0 = blockIdx.x * ROWS;
  const int p = r0 >> 5;              // unique path index (E=32, ROWS=4 -> uniform per block)

  const float ts0 = ts[0];
  const float dtv = ts[1] - ts0;
  const int lane = tid & 63;
  const int wrow = tid >> 6;          // 0..15; rows use wrow<4
  const float wr_lo = Wr[lane];
  const float wr_hi = Wr[lane + 64];
  const float ycv = ycp[p];

  // ---- init: z = zh = h0, xv = [ts0, h0, c0, 0] ----
  for (int idx = tid; idx < ROWS * H; idx += TPB) {
    int i = idx >> 7, h = idx & (H - 1);
    float v = h0u[p * H + h];
    zz[idx] = v; zzh[idx] = v;
    xv[i * KP + 1 + h] = v;
  }
  if (tid < ROWS * SIG) {
    int i = tid / SIG, j = tid % SIG;
    xv[i * KP + 1 + H + j] = c0u[p * SIG + j];
  }
  if (tid < ROWS) { xv[tid * KP] = ts0; xv[tid * KP + IN] = 0.f; }
  __syncthreads();

  // ---- f0, g0 ----
  layer_c256<TR>(WF1, fb1, xv, KP, IN, KP, pp, hA, tid);
  layer_c256<TR>(WF2, fb2, hA, M, M, M, pp, hB, tid);
  layer_c128<TR>(WF3, fb3, hB, M, pp, fo, tid);
  layer_c256<TR>(WG1, gb1, xv, KP, IN, KP, pp, hA, tid);
  layer_c256<TR>(WG2, gb2, hA, M, M, M, pp, hB, tid);
  layer_c512<TR>(WG3, gb3, hB, M, pp, go, tid);

  // ---- emit t=0 ----
  if (wrow < ROWS) {
    float part = zz[wrow * H + lane] * wr_lo + zz[wrow * H + lane + 64] * wr_hi;
    for (int off = 32; off; off >>= 1) part += __shfl_down(part, off, 64);
    if (lane == 0) {
      size_t o = ((size_t)(r0 + wrow) * L + 0) * 2;
      out[o] = ts0; out[o + 1] = part + ycv;
    }
  }
  __syncthreads();

  // ---- time loop ----
  for (int t = 1; t < L; t++) {
    const float t1 = ts[t];
    const float4* dwp = (const float4*)(dW + ((size_t)(t - 1) * BE + r0) * N);

    // phase A: zh1 = 2z - zh + fh*dt + gh.dW ; zmid = z + 0.5dt*fh + 0.5*gh.dW
    for (int e = tid; e < ROWS * H; e += TPB) {
      int i = e >> 7, h = e & (H - 1);
      float4 dwv = dwp[i];
      float4 g4 = *(const float4*)(go + i * (H * N) + h * 4);
      float gdot = g4.x * dwv.x + g4.y * dwv.y + g4.z * dwv.z + g4.w * dwv.w;
      float fh = fo[e];
      float zo = zz[e];
      float nzh = 2.f * zo - zzh[e] + fh * dtv + gdot;
      zz[e] = zo + 0.5f * dtv * fh + 0.5f * gdot;
      zzh[e] = nzh;
      xv[i * KP + 1 + h] = nzh;
    }
    if (tid < ROWS) xv[tid * KP] = t1;
    __syncthreads();

    // f1, g1 at (t1, zh1)
    layer_c256<TR>(WF1, fb1, xv, KP, IN, KP, pp, hA, tid);
    layer_c256<TR>(WF2, fb2, hA, M, M, M, pp, hB, tid);
    layer_c128<TR>(WF3, fb3, hB, M, pp, fo, tid);
    layer_c256<TR>(WG1, gb1, xv, KP, IN, KP, pp, hA, tid);
    layer_c256<TR>(WG2, gb2, hA, M, M, M, pp, hB, tid);
    layer_c512<TR>(WG3, gb3, hB, M, pp, go, tid);

    // phase B: z1 = zmid + 0.5dt*f1 + 0.5*g1.dW
    for (int e = tid; e < ROWS * H; e += TPB) {
      int i = e >> 7, h = e & (H - 1);
      float4 dwv = dwp[i];
      float4 g4 = *(const float4*)(go + i * (H * N) + h * 4);
      float gdot = g4.x * dwv.x + g4.y * dwv.y + g4.z * dwv.z + g4.w * dwv.w;
      zz[e] = zz[e] + 0.5f * dtv * fo[e] + 0.5f * gdot;
    }
    __syncthreads();

    // emit y_t
    if (wrow < ROWS) {
      float part = zz[wrow * H + lane] * wr_lo + zz[wrow * H + lane + 64] * wr_hi;
      for (int off = 32; off; off >>= 1) part += __shfl_down(part, off, 64);
      if (lane == 0) {
        size_t o = ((size_t)(r0 + wrow) * L + t) * 2;
        out[o] = t1; out[o + 1] = part + ycv;
      }
    }
    __syncthreads();
  }
}

// ---------------- launch ----------------
extern "C" void kernel_launch(void* const* d_in, const int* in_sizes, int n_in,
                              void* d_out, int out_size, void* d_ws, size_t ws_size,
                              hipStream_t stream) {
  const float* ts    = (const float*)d_in[0];
  const float* paths = (const float*)d_in[1];
  const float* dWn   = (const float*)d_in[2];
  const float* Wi    = (const float*)d_in[3];
  const float* bi    = (const float*)d_in[4];
  const float* fW1   = (const float*)d_in[5];
  const float* fb1   = (const float*)d_in[6];
  const float* fW2   = (const float*)d_in[7];
  const float* fb2   = (const float*)d_in[8];
  const float* fW3   = (const float*)d_in[9];
  const float* fb3   = (const float*)d_in[10];
  const float* gW1   = (const float*)d_in[11];
  const float* gb1   = (const float*)d_in[12];
  const float* gW2   = (const float*)d_in[13];
  const float* gb2   = (const float*)d_in[14];
  const float* gW3   = (const float*)d_in[15];
  const float* gb3   = (const float*)d_in[16];
  const float* Wr    = (const float*)d_in[17];
  const float* br    = (const float*)d_in[18];
  float* out = (float*)d_out;
  float* wsf = (float*)d_ws;

  const bool tr = ws_size >= WS_TOT * sizeof(float);
  if (tr) {
    prep_kernel<<<64, 256, 0, stream>>>(paths, Wi, bi, Wr, br,
                                        fW1, fW2, fW3, gW1, gW2, gW3,
                                        wsf, wsf + OFF_H0, wsf + OFF_C0, wsf + OFF_YC, 1);
    sde_kernel<true><<<NBLK, TPB, 0, stream>>>(
        ts, dWn, fb1, fb2, fb3, gb1, gb2, gb3, Wr,
        wsf + OFF_FW1, wsf + OFF_FW2, wsf + OFF_FW3,
        wsf + OFF_GW1, wsf + OFF_GW2, wsf + OFF_GW3,
        wsf + OFF_H0, wsf + OFF_C0, wsf + OFF_YC, out);
  } else {
    // small-workspace fallback: only h0/c0/yc in ws, weights read untransposed
    float* h0u = wsf;
    float* c0u = wsf + 32 * H;
    float* yc  = wsf + 32 * H + 32 * SIG;
    prep_kernel<<<1, 256, 0, stream>>>(paths, Wi, bi, Wr, br,
                                       fW1, fW2, fW3, gW1, gW2, gW3,
                                       wsf, h0u, c0u, yc, 0);
    sde_kernel<false><<<NBLK, TPB, 0, stream>>>(
        ts, dWn, fb1, fb2, fb3, gb1, gb2, gb3, Wr,
        fW1, fW2, fW3, gW1, gW2, gW3,
        h0u, c0u, yc, out);
  }
}